// Round 8
// baseline (2723.462 us; speedup 1.0000x reference)
//
#include <hip/hip_runtime.h>
#include <math.h>

typedef _Float16 f16;
typedef _Float16 f16x8 __attribute__((ext_vector_type(8)));
typedef float    f32x4 __attribute__((ext_vector_type(4)));
typedef unsigned int u32;
typedef unsigned long long u64;

#define NHEADS 128
#define KLEN   8192
#define DDIM   128
#define SDIM   256
#define NROWS  (NHEADS * KLEN)       // 1,048,576 k-rows
#define SCALE  1.2533141373155003f   // sqrt(pi/2)
#define TAU    2e-5f                 // suspect threshold (validated rounds 3 & 7)

// ---- workspace layout ----
// [0, 1MiB)            : qs16 f16 [128 heads][16 q][256 s]
// [1MiB, +64KiB)       : Gh_t f16 [256 s][128 d]  (hi, transposed)
// [+64K, +128K)        : Gl_t f16 [256 s][128 d]  (lo * 4096, transposed)
// [+128K, +256K)       : Gt   f32 [256 s][128 d]  (exact, transposed)
// [2MiB, 2MiB+32MiB)   : packed sign bits, u32[1M rows][8]
// suspect MASK (u32[1M rows][8], 32MB) lives in d_out (dead until est).
#define QS_OFF     0
#define GH_OFF     (1u << 20)
#define GL_OFF     ((1u << 20) + (64u << 10))
#define GT_OFF     ((1u << 20) + (128u << 10))
#define PACKED_OFF (2u << 20)

// ------------------------------------------------------------------
// Sequential f32 dot, d-ascending, single-rounding FMA per step —
// bitwise-matches the numpy reference path (validated round 3).
__device__ __forceinline__ float seq_dot_np(const float* __restrict__ a,
                                            const float* __restrict__ gcol) {
  float acc = 0.0f;
  #pragma unroll 8
  for (int d = 0; d < DDIM; ++d)
    acc = __builtin_fmaf(a[d], gcol[d], acc);
  return acc;
}

// ------------------------------------------------------------------
// prep: q_sketch = q @ G  (f32 accumulate, store f16)
__global__ void prep_qs_kernel(const float* __restrict__ q,
                               const float* __restrict__ G,
                               f16* __restrict__ qs16) {
  int idx = blockIdx.x * 256 + threadIdx.x;      // 524288
  int s  = idx & 255;
  int hq = idx >> 8;
  const float* qr = q + (size_t)hq * DDIM;
  float acc = 0.f;
  #pragma unroll 8
  for (int d = 0; d < DDIM; ++d) acc += qr[d] * G[d * SDIM + s];
  qs16[idx] = (f16)acc;
}

// prep: G -> f16 transposed hi + f16 transposed (lo*4096) + f32 exact copy
__global__ void prep_g_kernel(const float* __restrict__ G,
                              f16* __restrict__ gh, f16* __restrict__ gl,
                              float* __restrict__ gt) {
  int idx = blockIdx.x * 256 + threadIdx.x;      // 32768
  int d = idx & 127;
  int s = idx >> 7;
  float g = G[d * SDIM + s];
  f16 h = (f16)g;
  gh[s * DDIM + d] = h;
  gl[s * DDIM + d] = (f16)((g - (float)h) * 4096.0f);
  gt[s * DDIM + d] = g;
}

// ------------------------------------------------------------------
// Pass A: proj = k @ G via f16x3 MFMA emulation (round-3/7 arithmetic,
// bit-identical accumulation order). B (Gh+Gl, 128KB) staged ONCE per
// block into LDS, XOR-swizzled (byte ^= (s&7)<<4) -> conflict-free
// ds_read_b128. One barrier per block. 16 waves/block, 16 rows/wave,
// 2 row-iterations -> 512 rows/block; grid 2048.
__launch_bounds__(1024, 4)
__global__ void proj_sign_kernel(const float* __restrict__ kmat,
                                 const f16* __restrict__ gh,
                                 const f16* __restrict__ gl,
                                 u32* __restrict__ packed,
                                 u32* __restrict__ smask) {
  __shared__ __align__(16) char smem[131072];    // Bh [0,64K) + Bl [64K,128K)

  const int tid  = threadIdx.x;
  const int lane = tid & 63;
  const int w    = tid >> 6;                     // wave 0..15
  const int g4 = lane >> 4;
  const int ln = lane & 15;

  // ---- stage Gh+Gl -> LDS, swizzled; each thread 4 x 16B per buffer ----
  #pragma unroll
  for (int j = 0; j < 4; ++j) {
    int cidx = j * 1024 + tid;                   // 4096 chunks of 16B
    int s = cidx >> 4;
    int off = (cidx * 16) ^ ((s & 7) << 4);
    *(f16x8*)(smem + off)         = *(const f16x8*)(gh + (size_t)cidx * 8);
    *(f16x8*)(smem + 65536 + off) = *(const f16x8*)(gl + (size_t)cidx * 8);
  }
  __syncthreads();

  // ---- 2 iterations of 16 rows per wave ----
  for (int it = 0; it < 2; ++it) {
    const int base = blockIdx.x * 512 + it * 256 + w * 16;

    // A fragments (hi/lo f16 split) for 16 rows; A[m][kk]: m=lane&15,
    // kk=8*(lane>>4)+j
    f16x8 Ah[4], Al[4];
    {
      const float* kr = kmat + (size_t)(base + ln) * DDIM;
      #pragma unroll
      for (int c = 0; c < 4; ++c) {
        const float* p0 = kr + c * 32 + g4 * 8;
        float4 a0 = *(const float4*)p0;
        float4 a1 = *(const float4*)(p0 + 4);
        float af[8] = {a0.x, a0.y, a0.z, a0.w, a1.x, a1.y, a1.z, a1.w};
        f16x8 hh, ll;
        #pragma unroll
        for (int j = 0; j < 8; ++j) {
          f16 h = (f16)af[j];
          hh[j] = h;
          ll[j] = (f16)((af[j] - (float)h) * 4096.0f);
        }
        Ah[c] = hh;
        Al[c] = ll;
      }
    }

    u32 pw[8] = {0};   // packed sign words  (lane<16: row base+lane)
    u32 sw[8] = {0};   // suspect mask words

    #pragma unroll
    for (int tl = 0; tl < 16; ++tl) {            // 16 s-tiles of 16
      const int s = tl * 16 + ln;
      const int sx = (s & 7) << 4;               // XOR swizzle
      f16x8 Bh[4], Bl[4];
      #pragma unroll
      for (int c = 0; c < 4; ++c) {
        int off = (s * 256 + c * 64 + g4 * 16) ^ sx;
        Bh[c] = *(const f16x8*)(smem + off);
        Bl[c] = *(const f16x8*)(smem + 65536 + off);
      }
      // round-3 accumulation order (validated): ah chain, al chain
      f32x4 ah = {0,0,0,0}, al = {0,0,0,0};
      #pragma unroll
      for (int c = 0; c < 4; ++c) {
        ah = __builtin_amdgcn_mfma_f32_16x16x32_f16(Ah[c], Bh[c], ah, 0, 0, 0);
        al = __builtin_amdgcn_mfma_f32_16x16x32_f16(Ah[c], Bl[c], al, 0, 0, 0);
        al = __builtin_amdgcn_mfma_f32_16x16x32_f16(Al[c], Bh[c], al, 0, 0, 0);
      }
      float p[4];
      #pragma unroll
      for (int r = 0; r < 4; ++r)
        p[r] = ah[r] + al[r] * 2.44140625e-4f;   // 1/4096

      // sign ballots
      {
        u64 b0 = __ballot(p[0] > 0.0f ? 1 : 0);
        u64 b1 = __ballot(p[1] > 0.0f ? 1 : 0);
        u64 b2 = __ballot(p[2] > 0.0f ? 1 : 0);
        u64 b3 = __ballot(p[3] > 0.0f ? 1 : 0);
        if (lane < 16) {
          int r = lane & 3;
          u64 b = (r == 0) ? b0 : (r == 1) ? b1 : (r == 2) ? b2 : b3;
          u32 sh = 16u * (u32)(lane >> 2);
          pw[tl >> 1] |= ((u32)((b >> sh) & 0xffffu)) << (16 * (tl & 1));
        }
      }

      // suspect ballots, guarded (trip prob ~0.6% per tile at 2e-5)
      float mn = fminf(fminf(__builtin_fabsf(p[0]), __builtin_fabsf(p[1])),
                       fminf(__builtin_fabsf(p[2]), __builtin_fabsf(p[3])));
      if (__any(mn < TAU ? 1 : 0)) {
        u64 t0 = __ballot(__builtin_fabsf(p[0]) < TAU ? 1 : 0);
        u64 t1 = __ballot(__builtin_fabsf(p[1]) < TAU ? 1 : 0);
        u64 t2 = __ballot(__builtin_fabsf(p[2]) < TAU ? 1 : 0);
        u64 t3 = __ballot(__builtin_fabsf(p[3]) < TAU ? 1 : 0);
        if (lane < 16) {
          int r = lane & 3;
          u64 t = (r == 0) ? t0 : (r == 1) ? t1 : (r == 2) ? t2 : t3;
          u32 sh = 16u * (u32)(lane >> 2);
          sw[tl >> 1] |= ((u32)((t >> sh) & 0xffffu)) << (16 * (tl & 1));
        }
      }
    }

    if (lane < 16) {
      size_t row = (size_t)(base + lane);
      uint4 v0, v1, m0, m1;
      v0.x = pw[0]; v0.y = pw[1]; v0.z = pw[2]; v0.w = pw[3];
      v1.x = pw[4]; v1.y = pw[5]; v1.z = pw[6]; v1.w = pw[7];
      m0.x = sw[0]; m0.y = sw[1]; m0.z = sw[2]; m0.w = sw[3];
      m1.x = sw[4]; m1.y = sw[5]; m1.z = sw[6]; m1.w = sw[7];
      *(uint4*)(packed + row * 8)     = v0;
      *(uint4*)(packed + row * 8 + 4) = v1;
      *(uint4*)(smask  + row * 8)     = m0;
      *(uint4*)(smask  + row * 8 + 4) = m1;
    }
  }
}

// ------------------------------------------------------------------
// Pass B: one thread per k-row; ~6K suspects total -> mask-scan bound.
__global__ void fixup_kernel(const float* __restrict__ kmat,
                             const float* __restrict__ gt,
                             u32* __restrict__ packed,
                             const u32* __restrict__ smask) {
  int row = blockIdx.x * 256 + threadIdx.x;
  if (row >= NROWS) return;
  const u32* mp = smask + (size_t)row * 8;
  uint4 m0 = *(const uint4*)mp;
  uint4 m1 = *(const uint4*)(mp + 4);
  u32 mw[8] = {m0.x, m0.y, m0.z, m0.w, m1.x, m1.y, m1.z, m1.w};
  if (!(mw[0] | mw[1] | mw[2] | mw[3] | mw[4] | mw[5] | mw[6] | mw[7])) return;
  const float* a = kmat + (size_t)row * DDIM;
  #pragma unroll
  for (int wd = 0; wd < 8; ++wd) {
    u32 m = mw[wd];
    if (!m) continue;
    u32 pk = packed[(size_t)row * 8 + wd];
    while (m) {
      int b = __ffs(m) - 1;  m &= m - 1;
      int s = wd * 32 + b;
      float acc = seq_dot_np(a, gt + (size_t)s * DDIM);
      if (acc > 0.0f) pk |= (1u << b);
      else            pk &= ~(1u << b);
    }
    packed[(size_t)row * 8 + wd] = pk;
  }
}

// ------------------------------------------------------------------
// est = q_sketch @ sign^T, bits -> ±1 f16 on the fly, MFMA f16, f32 out
__launch_bounds__(256)
__global__ void est_kernel(const f16* __restrict__ qs16,
                           const u32* __restrict__ packed,
                           float* __restrict__ out) {
  const int tid  = threadIdx.x;
  const int lane = tid & 63;
  const int w    = tid >> 6;
  const int wg   = blockIdx.x;
  const int head   = wg >> 5;
  const int kchunk = (wg & 31) * 256;
  const int g4 = lane >> 4, ln = lane & 15;

  f16x8 aq[8];
  const f16* qb = qs16 + (size_t)head * 16 * SDIM;
  #pragma unroll
  for (int c = 0; c < 8; ++c)
    aq[c] = *(const f16x8*)(qb + ln * SDIM + c * 32 + g4 * 8);

  const int kb = kchunk + w * 64;
  #pragma unroll
  for (int kt = 0; kt < 4; ++kt) {
    int krow = kb + kt * 16 + ln;
    const u32* bp = packed + (size_t)(head * KLEN + krow) * 8;
    uint4 q0 = *(const uint4*)bp;
    uint4 q1 = *(const uint4*)(bp + 4);
    u32 b32[8] = {q0.x, q0.y, q0.z, q0.w, q1.x, q1.y, q1.z, q1.w};
    f32x4 acc = {0, 0, 0, 0};
    #pragma unroll
    for (int c = 0; c < 8; ++c) {
      u32 byte8 = (b32[c] >> (8 * g4)) & 0xffu;
      union { u32 u[4]; f16x8 h; } sv;
      #pragma unroll
      for (int pp = 0; pp < 4; ++pp) {
        u32 v = 0x3C003C00u;
        v |= ((byte8 >> (2 * pp))     & 1u) ? 0u : 0x8000u;
        v |= ((byte8 >> (2 * pp + 1)) & 1u) ? 0u : 0x80000000u;
        sv.u[pp] = v;
      }
      acc = __builtin_amdgcn_mfma_f32_16x16x32_f16(aq[c], sv.h, acc, 0, 0, 0);
    }
    float* ob = out + (size_t)(head * 16) * KLEN + kb + kt * 16 + ln;
    #pragma unroll
    for (int r = 0; r < 4; ++r) {
      int qrow = g4 * 4 + r;
      ob[(size_t)qrow * KLEN] = acc[r] * SCALE;
    }
  }
}

// ------------------------------------------------------------------
extern "C" void kernel_launch(void* const* d_in, const int* in_sizes, int n_in,
                              void* d_out, int out_size, void* d_ws, size_t ws_size,
                              hipStream_t stream) {
  const float* q = (const float*)d_in[0];
  const float* k = (const float*)d_in[1];
  const float* G = (const float*)d_in[2];
  float* out = (float*)d_out;
  char* ws = (char*)d_ws;

  f16*   qs16   = (f16*)(ws + QS_OFF);
  f16*   gh     = (f16*)(ws + GH_OFF);
  f16*   gl     = (f16*)(ws + GL_OFF);
  float* gt     = (float*)(ws + GT_OFF);
  u32*   packed = (u32*)(ws + PACKED_OFF);

  // suspect mask in d_out (32MB << 67MB); fully rewritten by proj_sign
  // each call; est overwrites d_out afterwards (stream-ordered).
  u32* smask = (u32*)d_out;

  prep_qs_kernel<<<2048, 256, 0, stream>>>(q, G, qs16);
  prep_g_kernel<<<128, 256, 0, stream>>>(G, gh, gl, gt);
  proj_sign_kernel<<<2048, 1024, 0, stream>>>(k, gh, gl, packed, smask);
  fixup_kernel<<<4096, 256, 0, stream>>>(k, gt, packed, smask);
  est_kernel<<<4096, 256, 0, stream>>>(qs16, packed, out);
}

// Round 9
// 377.698 us; speedup vs baseline: 7.2107x; 7.2107x over previous
//
#include <hip/hip_runtime.h>
#include <math.h>

typedef _Float16 f16;
typedef _Float16 f16x8 __attribute__((ext_vector_type(8)));
typedef float    f32x4 __attribute__((ext_vector_type(4)));
typedef unsigned int u32;
typedef unsigned long long u64;

#define NHEADS 128
#define KLEN   8192
#define DDIM   128
#define SDIM   256
#define NROWS  (NHEADS * KLEN)       // 1,048,576 k-rows
#define SCALE  1.2533141373155003f   // sqrt(pi/2)
#define TAU    2e-5f                 // suspect threshold (validated rounds 3 & 7)

// ---- workspace layout ----
// [0, 1MiB)            : qs16 f16 [128 heads][16 q][256 s]
// [1MiB, +64KiB)       : Gh_t f16 [256 s][128 d]  (hi, transposed)
// [+64K, +128K)        : Gl_t f16 [256 s][128 d]  (lo * 4096, transposed)
// [+128K, +256K)       : Gt   f32 [256 s][128 d]  (exact, transposed)
// [2MiB, 2MiB+32MiB)   : packed sign bits, u32[1M rows][8]
// suspect MASK (u32[1M rows][8], 32MB) lives in d_out (dead until est).
#define QS_OFF     0
#define GH_OFF     (1u << 20)
#define GL_OFF     ((1u << 20) + (64u << 10))
#define GT_OFF     ((1u << 20) + (128u << 10))
#define PACKED_OFF (2u << 20)

// ------------------------------------------------------------------
// Sequential f32 dot, d-ascending, single-rounding FMA per step —
// bitwise-matches the numpy reference path (validated round 3).
__device__ __forceinline__ float seq_dot_np(const float* __restrict__ a,
                                            const float* __restrict__ gcol) {
  float acc = 0.0f;
  #pragma unroll 8
  for (int d = 0; d < DDIM; ++d)
    acc = __builtin_fmaf(a[d], gcol[d], acc);
  return acc;
}

// ------------------------------------------------------------------
// prep: q_sketch = q @ G  (f32 accumulate, store f16)
__global__ void prep_qs_kernel(const float* __restrict__ q,
                               const float* __restrict__ G,
                               f16* __restrict__ qs16) {
  int idx = blockIdx.x * 256 + threadIdx.x;      // 524288
  int s  = idx & 255;
  int hq = idx >> 8;
  const float* qr = q + (size_t)hq * DDIM;
  float acc = 0.f;
  #pragma unroll 8
  for (int d = 0; d < DDIM; ++d) acc += qr[d] * G[d * SDIM + s];
  qs16[idx] = (f16)acc;
}

// prep: G -> f16 transposed hi + f16 transposed (lo*4096) + f32 exact copy
__global__ void prep_g_kernel(const float* __restrict__ G,
                              f16* __restrict__ gh, f16* __restrict__ gl,
                              float* __restrict__ gt) {
  int idx = blockIdx.x * 256 + threadIdx.x;      // 32768
  int d = idx & 127;
  int s = idx >> 7;
  float g = G[d * SDIM + s];
  f16 h = (f16)g;
  gh[s * DDIM + d] = h;
  gl[s * DDIM + d] = (f16)((g - (float)h) * 4096.0f);
  gt[s * DDIM + d] = g;
}

// ------------------------------------------------------------------
// Pass A: proj = k @ G via f16x3 MFMA emulation (round-3/7 arithmetic,
// bit-identical). Whole Gh+Gl (128KB) staged ONCE per block into LDS,
// XOR-swizzled; one barrier. 8 waves/block (512 thr), 32 rows/wave,
// 256 rows/block, grid 4096. No min-waves clamp -> no spill (R8 lesson).
__launch_bounds__(512)
__global__ void proj_sign_kernel(const float* __restrict__ kmat,
                                 const f16* __restrict__ gh,
                                 const f16* __restrict__ gl,
                                 u32* __restrict__ packed,
                                 u32* __restrict__ smask) {
  __shared__ __align__(16) char smem[131072];    // Bh [0,64K) + Bl [64K,128K)

  const int tid  = threadIdx.x;
  const int lane = tid & 63;
  const int w    = tid >> 6;                     // wave 0..7
  const int g4 = lane >> 4;
  const int ln = lane & 15;

  // ---- stage Gh+Gl -> LDS, swizzled; each thread 8 x 16B per buffer ----
  #pragma unroll
  for (int j = 0; j < 8; ++j) {
    int cidx = j * 512 + tid;                    // 4096 chunks of 16B
    int s = cidx >> 4;
    int off = (cidx * 16) ^ ((s & 7) << 4);
    *(f16x8*)(smem + off)         = *(const f16x8*)(gh + (size_t)cidx * 8);
    *(f16x8*)(smem + 65536 + off) = *(const f16x8*)(gl + (size_t)cidx * 8);
  }
  __syncthreads();

  const int base = blockIdx.x * 256 + w * 32;    // this wave's 32 rows

  // ---- A fragments (hi/lo f16 split) for 32 rows (2 blocks of 16) ----
  // A[m][kk]: m = lane&15, kk = 8*(lane>>4)+j
  f16x8 Ah[2][4], Al[2][4];
  #pragma unroll
  for (int rb = 0; rb < 2; ++rb) {
    const float* kr = kmat + (size_t)(base + rb * 16 + ln) * DDIM;
    #pragma unroll
    for (int c = 0; c < 4; ++c) {
      const float* p0 = kr + c * 32 + g4 * 8;
      float4 a0 = *(const float4*)p0;
      float4 a1 = *(const float4*)(p0 + 4);
      float af[8] = {a0.x, a0.y, a0.z, a0.w, a1.x, a1.y, a1.z, a1.w};
      f16x8 hh, ll;
      #pragma unroll
      for (int j = 0; j < 8; ++j) {
        f16 h = (f16)af[j];
        hh[j] = h;
        ll[j] = (f16)((af[j] - (float)h) * 4096.0f);
      }
      Ah[rb][c] = hh;
      Al[rb][c] = ll;
    }
  }

  u32 pw[2][8] = {{0}};   // packed sign words  (lane<16: row rb*16+lane)
  u32 sw[2][8] = {{0}};   // suspect mask words

  #pragma unroll
  for (int tl = 0; tl < 16; ++tl) {              // 16 s-tiles of 16
    const int s = tl * 16 + ln;
    const int sx = (s & 7) << 4;                 // XOR swizzle
    f16x8 Bh[4], Bl[4];
    #pragma unroll
    for (int c = 0; c < 4; ++c) {
      int off = (s * 256 + c * 64 + g4 * 16) ^ sx;
      Bh[c] = *(const f16x8*)(smem + off);
      Bl[c] = *(const f16x8*)(smem + 65536 + off);
    }
    // round-3/7 accumulation order (validated): ah chain, al chain
    f32x4 ah0 = {0,0,0,0}, al0 = {0,0,0,0};
    f32x4 ah1 = {0,0,0,0}, al1 = {0,0,0,0};
    #pragma unroll
    for (int c = 0; c < 4; ++c) {
      ah0 = __builtin_amdgcn_mfma_f32_16x16x32_f16(Ah[0][c], Bh[c], ah0, 0, 0, 0);
      al0 = __builtin_amdgcn_mfma_f32_16x16x32_f16(Ah[0][c], Bl[c], al0, 0, 0, 0);
      al0 = __builtin_amdgcn_mfma_f32_16x16x32_f16(Al[0][c], Bh[c], al0, 0, 0, 0);
      ah1 = __builtin_amdgcn_mfma_f32_16x16x32_f16(Ah[1][c], Bh[c], ah1, 0, 0, 0);
      al1 = __builtin_amdgcn_mfma_f32_16x16x32_f16(Ah[1][c], Bl[c], al1, 0, 0, 0);
      al1 = __builtin_amdgcn_mfma_f32_16x16x32_f16(Al[1][c], Bh[c], al1, 0, 0, 0);
    }
    float p[2][4];
    #pragma unroll
    for (int r = 0; r < 4; ++r) {
      p[0][r] = ah0[r] + al0[r] * 2.44140625e-4f;   // 1/4096
      p[1][r] = ah1[r] + al1[r] * 2.44140625e-4f;
    }

    // ---- sign ballots ----
    #pragma unroll
    for (int rb = 0; rb < 2; ++rb) {
      u64 b0 = __ballot(p[rb][0] > 0.0f ? 1 : 0);
      u64 b1 = __ballot(p[rb][1] > 0.0f ? 1 : 0);
      u64 b2 = __ballot(p[rb][2] > 0.0f ? 1 : 0);
      u64 b3 = __ballot(p[rb][3] > 0.0f ? 1 : 0);
      if (lane < 16) {
        int r = lane & 3;
        u64 b = (r == 0) ? b0 : (r == 1) ? b1 : (r == 2) ? b2 : b3;
        u32 sh = 16u * (u32)(lane >> 2);
        pw[rb][tl >> 1] |= ((u32)((b >> sh) & 0xffffu)) << (16 * (tl & 1));
      }
    }

    // ---- suspect ballots, guarded (trip prob ~1% per tile at 2e-5) ----
    float mn = p[0][0];
    #pragma unroll
    for (int rb = 0; rb < 2; ++rb)
      #pragma unroll
      for (int r = 0; r < 4; ++r)
        mn = fminf(mn, __builtin_fabsf(p[rb][r]));
    if (__any(mn < TAU ? 1 : 0)) {
      #pragma unroll
      for (int rb = 0; rb < 2; ++rb) {
        u64 t0 = __ballot(__builtin_fabsf(p[rb][0]) < TAU ? 1 : 0);
        u64 t1 = __ballot(__builtin_fabsf(p[rb][1]) < TAU ? 1 : 0);
        u64 t2 = __ballot(__builtin_fabsf(p[rb][2]) < TAU ? 1 : 0);
        u64 t3 = __ballot(__builtin_fabsf(p[rb][3]) < TAU ? 1 : 0);
        if (lane < 16) {
          int r = lane & 3;
          u64 t = (r == 0) ? t0 : (r == 1) ? t1 : (r == 2) ? t2 : t3;
          u32 sh = 16u * (u32)(lane >> 2);
          sw[rb][tl >> 1] |= ((u32)((t >> sh) & 0xffffu)) << (16 * (tl & 1));
        }
      }
    }
  }

  if (lane < 16) {
    #pragma unroll
    for (int rb = 0; rb < 2; ++rb) {
      size_t row = (size_t)(base + rb * 16 + lane);
      uint4 v0, v1, m0, m1;
      v0.x = pw[rb][0]; v0.y = pw[rb][1]; v0.z = pw[rb][2]; v0.w = pw[rb][3];
      v1.x = pw[rb][4]; v1.y = pw[rb][5]; v1.z = pw[rb][6]; v1.w = pw[rb][7];
      m0.x = sw[rb][0]; m0.y = sw[rb][1]; m0.z = sw[rb][2]; m0.w = sw[rb][3];
      m1.x = sw[rb][4]; m1.y = sw[rb][5]; m1.z = sw[rb][6]; m1.w = sw[rb][7];
      *(uint4*)(packed + row * 8)     = v0;
      *(uint4*)(packed + row * 8 + 4) = v1;
      *(uint4*)(smask  + row * 8)     = m0;
      *(uint4*)(smask  + row * 8 + 4) = m1;
    }
  }
}

// ------------------------------------------------------------------
// Pass B: one thread per k-row; ~6K suspects total -> mask-scan bound.
__global__ void fixup_kernel(const float* __restrict__ kmat,
                             const float* __restrict__ gt,
                             u32* __restrict__ packed,
                             const u32* __restrict__ smask) {
  int row = blockIdx.x * 256 + threadIdx.x;
  if (row >= NROWS) return;
  const u32* mp = smask + (size_t)row * 8;
  uint4 m0 = *(const uint4*)mp;
  uint4 m1 = *(const uint4*)(mp + 4);
  u32 mw[8] = {m0.x, m0.y, m0.z, m0.w, m1.x, m1.y, m1.z, m1.w};
  if (!(mw[0] | mw[1] | mw[2] | mw[3] | mw[4] | mw[5] | mw[6] | mw[7])) return;
  const float* a = kmat + (size_t)row * DDIM;
  #pragma unroll
  for (int wd = 0; wd < 8; ++wd) {
    u32 m = mw[wd];
    if (!m) continue;
    u32 pk = packed[(size_t)row * 8 + wd];
    while (m) {
      int b = __ffs(m) - 1;  m &= m - 1;
      int s = wd * 32 + b;
      float acc = seq_dot_np(a, gt + (size_t)s * DDIM);
      if (acc > 0.0f) pk |= (1u << b);
      else            pk &= ~(1u << b);
    }
    packed[(size_t)row * 8 + wd] = pk;
  }
}

// ------------------------------------------------------------------
// est = q_sketch @ sign^T, bits -> ±1 f16 on the fly, MFMA f16, f32 out
__launch_bounds__(256)
__global__ void est_kernel(const f16* __restrict__ qs16,
                           const u32* __restrict__ packed,
                           float* __restrict__ out) {
  const int tid  = threadIdx.x;
  const int lane = tid & 63;
  const int w    = tid >> 6;
  const int wg   = blockIdx.x;
  const int head   = wg >> 5;
  const int kchunk = (wg & 31) * 256;
  const int g4 = lane >> 4, ln = lane & 15;

  f16x8 aq[8];
  const f16* qb = qs16 + (size_t)head * 16 * SDIM;
  #pragma unroll
  for (int c = 0; c < 8; ++c)
    aq[c] = *(const f16x8*)(qb + ln * SDIM + c * 32 + g4 * 8);

  const int kb = kchunk + w * 64;
  #pragma unroll
  for (int kt = 0; kt < 4; ++kt) {
    int krow = kb + kt * 16 + ln;
    const u32* bp = packed + (size_t)(head * KLEN + krow) * 8;
    uint4 q0 = *(const uint4*)bp;
    uint4 q1 = *(const uint4*)(bp + 4);
    u32 b32[8] = {q0.x, q0.y, q0.z, q0.w, q1.x, q1.y, q1.z, q1.w};
    f32x4 acc = {0, 0, 0, 0};
    #pragma unroll
    for (int c = 0; c < 8; ++c) {
      u32 byte8 = (b32[c] >> (8 * g4)) & 0xffu;
      union { u32 u[4]; f16x8 h; } sv;
      #pragma unroll
      for (int pp = 0; pp < 4; ++pp) {
        u32 v = 0x3C003C00u;
        v |= ((byte8 >> (2 * pp))     & 1u) ? 0u : 0x8000u;
        v |= ((byte8 >> (2 * pp + 1)) & 1u) ? 0u : 0x80000000u;
        sv.u[pp] = v;
      }
      acc = __builtin_amdgcn_mfma_f32_16x16x32_f16(aq[c], sv.h, acc, 0, 0, 0);
    }
    float* ob = out + (size_t)(head * 16) * KLEN + kb + kt * 16 + ln;
    #pragma unroll
    for (int r = 0; r < 4; ++r) {
      int qrow = g4 * 4 + r;
      ob[(size_t)qrow * KLEN] = acc[r] * SCALE;
    }
  }
}

// ------------------------------------------------------------------
extern "C" void kernel_launch(void* const* d_in, const int* in_sizes, int n_in,
                              void* d_out, int out_size, void* d_ws, size_t ws_size,
                              hipStream_t stream) {
  const float* q = (const float*)d_in[0];
  const float* k = (const float*)d_in[1];
  const float* G = (const float*)d_in[2];
  float* out = (float*)d_out;
  char* ws = (char*)d_ws;

  f16*   qs16   = (f16*)(ws + QS_OFF);
  f16*   gh     = (f16*)(ws + GH_OFF);
  f16*   gl     = (f16*)(ws + GL_OFF);
  float* gt     = (float*)(ws + GT_OFF);
  u32*   packed = (u32*)(ws + PACKED_OFF);

  // suspect mask in d_out (32MB << 67MB); fully rewritten by proj_sign
  // each call; est overwrites d_out afterwards (stream-ordered).
  u32* smask = (u32*)d_out;

  prep_qs_kernel<<<2048, 256, 0, stream>>>(q, G, qs16);
  prep_g_kernel<<<128, 256, 0, stream>>>(G, gh, gl, gt);
  proj_sign_kernel<<<4096, 512, 0, stream>>>(k, gh, gl, packed, smask);
  fixup_kernel<<<4096, 256, 0, stream>>>(k, gt, packed, smask);
  est_kernel<<<4096, 256, 0, stream>>>(qs16, packed, out);
}

// Round 10
// 363.408 us; speedup vs baseline: 7.4942x; 1.0393x over previous
//
#include <hip/hip_runtime.h>
#include <math.h>

typedef _Float16 f16;
typedef _Float16 f16x8 __attribute__((ext_vector_type(8)));
typedef float    f32x4 __attribute__((ext_vector_type(4)));
typedef unsigned int u32;
typedef unsigned long long u64;

#define NHEADS 128
#define KLEN   8192
#define DDIM   128
#define SDIM   256
#define NROWS  (NHEADS * KLEN)       // 1,048,576 k-rows
#define SCALE  1.2533141373155003f   // sqrt(pi/2)
#define TAU    2e-5f                 // suspect threshold (validated rounds 3/7/9)

// ---- workspace layout ----
// [0, 1MiB)            : qs16 f16 [128 heads][16 q][256 s]
// [1MiB, +64KiB)       : Gh_t f16 [256 s][128 d]  (hi, transposed)
// [+64K, +128K)        : Gl_t f16 [256 s][128 d]  (lo * 4096, transposed)
// [+128K, +256K)       : Gt   f32 [256 s][128 d]  (exact, transposed)
// [2MiB, 2MiB+32MiB)   : packed sign bits, u32[1M rows][8]
// suspect MASK (u32[1M rows][8], 32MB) lives in d_out (dead until est).
#define QS_OFF     0
#define GH_OFF     (1u << 20)
#define GL_OFF     ((1u << 20) + (64u << 10))
#define GT_OFF     ((1u << 20) + (128u << 10))
#define PACKED_OFF (2u << 20)

// ------------------------------------------------------------------
// Sequential f32 dot, d-ascending, single-rounding FMA per step —
// bitwise-matches the numpy reference path (validated round 3).
__device__ __forceinline__ float seq_dot_np(const float* __restrict__ a,
                                            const float* __restrict__ gcol) {
  float acc = 0.0f;
  #pragma unroll 8
  for (int d = 0; d < DDIM; ++d)
    acc = __builtin_fmaf(a[d], gcol[d], acc);
  return acc;
}

// ------------------------------------------------------------------
// prep: q_sketch = q @ G  (f32 accumulate, store f16)
__global__ void prep_qs_kernel(const float* __restrict__ q,
                               const float* __restrict__ G,
                               f16* __restrict__ qs16) {
  int idx = blockIdx.x * 256 + threadIdx.x;      // 524288
  int s  = idx & 255;
  int hq = idx >> 8;
  const float* qr = q + (size_t)hq * DDIM;
  float acc = 0.f;
  #pragma unroll 8
  for (int d = 0; d < DDIM; ++d) acc += qr[d] * G[d * SDIM + s];
  qs16[idx] = (f16)acc;
}

// prep: G -> f16 transposed hi + f16 transposed (lo*4096) + f32 exact copy
__global__ void prep_g_kernel(const float* __restrict__ G,
                              f16* __restrict__ gh, f16* __restrict__ gl,
                              float* __restrict__ gt) {
  int idx = blockIdx.x * 256 + threadIdx.x;      // 32768
  int d = idx & 127;
  int s = idx >> 7;
  float g = G[d * SDIM + s];
  f16 h = (f16)g;
  gh[s * DDIM + d] = h;
  gl[s * DDIM + d] = (f16)((g - (float)h) * 4096.0f);
  gt[s * DDIM + d] = g;
}

// ------------------------------------------------------------------
// Pass A: proj = k @ G via f16x3 MFMA emulation. Whole Gh+Gl (128KB)
// staged ONCE per block into LDS, XOR-swizzled; one barrier.
// 16 waves/block (1024 thr, NO min-waves clamp -> no spill, R8 lesson),
// 32 rows/wave, 512 rows/block, grid 2048 -> 4 waves/SIMD.
// al accumulator split into two independent chains (6 chains/tile ILP).
__launch_bounds__(1024)
__global__ void proj_sign_kernel(const float* __restrict__ kmat,
                                 const f16* __restrict__ gh,
                                 const f16* __restrict__ gl,
                                 u32* __restrict__ packed,
                                 u32* __restrict__ smask) {
  __shared__ __align__(16) char smem[131072];    // Bh [0,64K) + Bl [64K,128K)

  const int tid  = threadIdx.x;
  const int lane = tid & 63;
  const int w    = tid >> 6;                     // wave 0..15
  const int g4 = lane >> 4;
  const int ln = lane & 15;

  // ---- stage Gh+Gl -> LDS, swizzled; each thread 4 x 16B per buffer ----
  #pragma unroll
  for (int j = 0; j < 4; ++j) {
    int cidx = j * 1024 + tid;                   // 4096 chunks of 16B
    int s = cidx >> 4;
    int off = (cidx * 16) ^ ((s & 7) << 4);
    *(f16x8*)(smem + off)         = *(const f16x8*)(gh + (size_t)cidx * 8);
    *(f16x8*)(smem + 65536 + off) = *(const f16x8*)(gl + (size_t)cidx * 8);
  }
  __syncthreads();

  const int base = blockIdx.x * 512 + w * 32;    // this wave's 32 rows

  // ---- A fragments (hi/lo f16 split) for 32 rows (2 blocks of 16) ----
  // A[m][kk]: m = lane&15, kk = 8*(lane>>4)+j
  f16x8 Ah[2][4], Al[2][4];
  #pragma unroll
  for (int rb = 0; rb < 2; ++rb) {
    const float* kr = kmat + (size_t)(base + rb * 16 + ln) * DDIM;
    #pragma unroll
    for (int c = 0; c < 4; ++c) {
      const float* p0 = kr + c * 32 + g4 * 8;
      float4 a0 = *(const float4*)p0;
      float4 a1 = *(const float4*)(p0 + 4);
      float af[8] = {a0.x, a0.y, a0.z, a0.w, a1.x, a1.y, a1.z, a1.w};
      f16x8 hh, ll;
      #pragma unroll
      for (int j = 0; j < 8; ++j) {
        f16 h = (f16)af[j];
        hh[j] = h;
        ll[j] = (f16)((af[j] - (float)h) * 4096.0f);
      }
      Ah[rb][c] = hh;
      Al[rb][c] = ll;
    }
  }

  u32 pw[2][8] = {{0}};   // packed sign words  (lane<16: row rb*16+lane)
  u32 sw[2][8] = {{0}};   // suspect mask words

  #pragma unroll
  for (int tl = 0; tl < 16; ++tl) {              // 16 s-tiles of 16
    const int s = tl * 16 + ln;
    const int sx = (s & 7) << 4;                 // XOR swizzle
    f16x8 Bh[4], Bl[4];
    #pragma unroll
    for (int c = 0; c < 4; ++c) {
      int off = (s * 256 + c * 64 + g4 * 16) ^ sx;
      Bh[c] = *(const f16x8*)(smem + off);
      Bl[c] = *(const f16x8*)(smem + 65536 + off);
    }
    // f16x3 emulation, 6 INDEPENDENT 4-MFMA chains (ILP). Summation
    // order differs from np; fine since emul err ~1e-6 << TAU.
    f32x4 ah0 = {0,0,0,0}, aa0 = {0,0,0,0}, ab0 = {0,0,0,0};
    f32x4 ah1 = {0,0,0,0}, aa1 = {0,0,0,0}, ab1 = {0,0,0,0};
    #pragma unroll
    for (int c = 0; c < 4; ++c) {
      ah0 = __builtin_amdgcn_mfma_f32_16x16x32_f16(Ah[0][c], Bh[c], ah0, 0, 0, 0);
      aa0 = __builtin_amdgcn_mfma_f32_16x16x32_f16(Ah[0][c], Bl[c], aa0, 0, 0, 0);
      ab0 = __builtin_amdgcn_mfma_f32_16x16x32_f16(Al[0][c], Bh[c], ab0, 0, 0, 0);
      ah1 = __builtin_amdgcn_mfma_f32_16x16x32_f16(Ah[1][c], Bh[c], ah1, 0, 0, 0);
      aa1 = __builtin_amdgcn_mfma_f32_16x16x32_f16(Ah[1][c], Bl[c], aa1, 0, 0, 0);
      ab1 = __builtin_amdgcn_mfma_f32_16x16x32_f16(Al[1][c], Bh[c], ab1, 0, 0, 0);
    }
    float p[2][4];
    #pragma unroll
    for (int r = 0; r < 4; ++r) {
      p[0][r] = ah0[r] + (aa0[r] + ab0[r]) * 2.44140625e-4f;   // 1/4096
      p[1][r] = ah1[r] + (aa1[r] + ab1[r]) * 2.44140625e-4f;
    }

    // ---- sign ballots ----
    #pragma unroll
    for (int rb = 0; rb < 2; ++rb) {
      u64 b0 = __ballot(p[rb][0] > 0.0f ? 1 : 0);
      u64 b1 = __ballot(p[rb][1] > 0.0f ? 1 : 0);
      u64 b2 = __ballot(p[rb][2] > 0.0f ? 1 : 0);
      u64 b3 = __ballot(p[rb][3] > 0.0f ? 1 : 0);
      if (lane < 16) {
        int r = lane & 3;
        u64 b = (r == 0) ? b0 : (r == 1) ? b1 : (r == 2) ? b2 : b3;
        u32 sh = 16u * (u32)(lane >> 2);
        pw[rb][tl >> 1] |= ((u32)((b >> sh) & 0xffffu)) << (16 * (tl & 1));
      }
    }

    // ---- suspect ballots, guarded (trip prob ~1% per tile at 2e-5) ----
    float mn = __builtin_fabsf(p[0][0]);
    #pragma unroll
    for (int rb = 0; rb < 2; ++rb)
      #pragma unroll
      for (int r = 0; r < 4; ++r)
        mn = fminf(mn, __builtin_fabsf(p[rb][r]));
    if (__any(mn < TAU ? 1 : 0)) {
      #pragma unroll
      for (int rb = 0; rb < 2; ++rb) {
        u64 t0 = __ballot(__builtin_fabsf(p[rb][0]) < TAU ? 1 : 0);
        u64 t1 = __ballot(__builtin_fabsf(p[rb][1]) < TAU ? 1 : 0);
        u64 t2 = __ballot(__builtin_fabsf(p[rb][2]) < TAU ? 1 : 0);
        u64 t3 = __ballot(__builtin_fabsf(p[rb][3]) < TAU ? 1 : 0);
        if (lane < 16) {
          int r = lane & 3;
          u64 t = (r == 0) ? t0 : (r == 1) ? t1 : (r == 2) ? t2 : t3;
          u32 sh = 16u * (u32)(lane >> 2);
          sw[rb][tl >> 1] |= ((u32)((t >> sh) & 0xffffu)) << (16 * (tl & 1));
        }
      }
    }
  }

  if (lane < 16) {
    #pragma unroll
    for (int rb = 0; rb < 2; ++rb) {
      size_t row = (size_t)(base + rb * 16 + lane);
      uint4 v0, v1, m0, m1;
      v0.x = pw[rb][0]; v0.y = pw[rb][1]; v0.z = pw[rb][2]; v0.w = pw[rb][3];
      v1.x = pw[rb][4]; v1.y = pw[rb][5]; v1.z = pw[rb][6]; v1.w = pw[rb][7];
      m0.x = sw[rb][0]; m0.y = sw[rb][1]; m0.z = sw[rb][2]; m0.w = sw[rb][3];
      m1.x = sw[rb][4]; m1.y = sw[rb][5]; m1.z = sw[rb][6]; m1.w = sw[rb][7];
      *(uint4*)(packed + row * 8)     = v0;
      *(uint4*)(packed + row * 8 + 4) = v1;
      *(uint4*)(smask  + row * 8)     = m0;
      *(uint4*)(smask  + row * 8 + 4) = m1;
    }
  }
}

// ------------------------------------------------------------------
// Pass B: one thread per k-row; ~6K suspects total -> mask-scan bound.
__global__ void fixup_kernel(const float* __restrict__ kmat,
                             const float* __restrict__ gt,
                             u32* __restrict__ packed,
                             const u32* __restrict__ smask) {
  int row = blockIdx.x * 256 + threadIdx.x;
  if (row >= NROWS) return;
  const u32* mp = smask + (size_t)row * 8;
  uint4 m0 = *(const uint4*)mp;
  uint4 m1 = *(const uint4*)(mp + 4);
  u32 mw[8] = {m0.x, m0.y, m0.z, m0.w, m1.x, m1.y, m1.z, m1.w};
  if (!(mw[0] | mw[1] | mw[2] | mw[3] | mw[4] | mw[5] | mw[6] | mw[7])) return;
  const float* a = kmat + (size_t)row * DDIM;
  #pragma unroll
  for (int wd = 0; wd < 8; ++wd) {
    u32 m = mw[wd];
    if (!m) continue;
    u32 pk = packed[(size_t)row * 8 + wd];
    while (m) {
      int b = __ffs(m) - 1;  m &= m - 1;
      int s = wd * 32 + b;
      float acc = seq_dot_np(a, gt + (size_t)s * DDIM);
      if (acc > 0.0f) pk |= (1u << b);
      else            pk &= ~(1u << b);
    }
    packed[(size_t)row * 8 + wd] = pk;
  }
}

// ------------------------------------------------------------------
// est = q_sketch @ sign^T, bits -> ±1 f16 on the fly, MFMA f16, f32 out
__launch_bounds__(256)
__global__ void est_kernel(const f16* __restrict__ qs16,
                           const u32* __restrict__ packed,
                           float* __restrict__ out) {
  const int tid  = threadIdx.x;
  const int lane = tid & 63;
  const int w    = tid >> 6;
  const int wg   = blockIdx.x;
  const int head   = wg >> 5;
  const int kchunk = (wg & 31) * 256;
  const int g4 = lane >> 4, ln = lane & 15;

  f16x8 aq[8];
  const f16* qb = qs16 + (size_t)head * 16 * SDIM;
  #pragma unroll
  for (int c = 0; c < 8; ++c)
    aq[c] = *(const f16x8*)(qb + ln * SDIM + c * 32 + g4 * 8);

  const int kb = kchunk + w * 64;
  #pragma unroll
  for (int kt = 0; kt < 4; ++kt) {
    int krow = kb + kt * 16 + ln;
    const u32* bp = packed + (size_t)(head * KLEN + krow) * 8;
    uint4 q0 = *(const uint4*)bp;
    uint4 q1 = *(const uint4*)(bp + 4);
    u32 b32[8] = {q0.x, q0.y, q0.z, q0.w, q1.x, q1.y, q1.z, q1.w};
    f32x4 acc = {0, 0, 0, 0};
    #pragma unroll
    for (int c = 0; c < 8; ++c) {
      u32 byte8 = (b32[c] >> (8 * g4)) & 0xffu;
      union { u32 u[4]; f16x8 h; } sv;
      #pragma unroll
      for (int pp = 0; pp < 4; ++pp) {
        u32 v = 0x3C003C00u;
        v |= ((byte8 >> (2 * pp))     & 1u) ? 0u : 0x8000u;
        v |= ((byte8 >> (2 * pp + 1)) & 1u) ? 0u : 0x80000000u;
        sv.u[pp] = v;
      }
      acc = __builtin_amdgcn_mfma_f32_16x16x32_f16(aq[c], sv.h, acc, 0, 0, 0);
    }
    float* ob = out + (size_t)(head * 16) * KLEN + kb + kt * 16 + ln;
    #pragma unroll
    for (int r = 0; r < 4; ++r) {
      int qrow = g4 * 4 + r;
      ob[(size_t)qrow * KLEN] = acc[r] * SCALE;
    }
  }
}

// ------------------------------------------------------------------
extern "C" void kernel_launch(void* const* d_in, const int* in_sizes, int n_in,
                              void* d_out, int out_size, void* d_ws, size_t ws_size,
                              hipStream_t stream) {
  const float* q = (const float*)d_in[0];
  const float* k = (const float*)d_in[1];
  const float* G = (const float*)d_in[2];
  float* out = (float*)d_out;
  char* ws = (char*)d_ws;

  f16*   qs16   = (f16*)(ws + QS_OFF);
  f16*   gh     = (f16*)(ws + GH_OFF);
  f16*   gl     = (f16*)(ws + GL_OFF);
  float* gt     = (float*)(ws + GT_OFF);
  u32*   packed = (u32*)(ws + PACKED_OFF);

  // suspect mask in d_out (32MB << 67MB); fully rewritten by proj_sign
  // each call; est overwrites d_out afterwards (stream-ordered).
  u32* smask = (u32*)d_out;

  prep_qs_kernel<<<2048, 256, 0, stream>>>(q, G, qs16);
  prep_g_kernel<<<128, 256, 0, stream>>>(G, gh, gl, gt);
  proj_sign_kernel<<<2048, 1024, 0, stream>>>(k, gh, gl, packed, smask);
  fixup_kernel<<<4096, 256, 0, stream>>>(k, gt, packed, smask);
  est_kernel<<<4096, 256, 0, stream>>>(qs16, packed, out);
}

// Round 11
// 356.003 us; speedup vs baseline: 7.6501x; 1.0208x over previous
//
#include <hip/hip_runtime.h>
#include <math.h>

typedef _Float16 f16;
typedef _Float16 f16x8 __attribute__((ext_vector_type(8)));
typedef float    f32x4 __attribute__((ext_vector_type(4)));
typedef unsigned int u32;
typedef unsigned long long u64;

#define NHEADS 128
#define KLEN   8192
#define DDIM   128
#define SDIM   256
#define NROWS  (NHEADS * KLEN)       // 1,048,576 k-rows
#define SCALE  1.2533141373155003f   // sqrt(pi/2)
#define TAU    2e-5f                 // suspect threshold (validated rounds 3/7/9)

// ---- workspace layout ----
// [0, 1MiB)            : qs16 f16 [128 heads][16 q][256 s]
// [1MiB, +64KiB)       : Gh_t f16 [256 s][128 d]  (hi, transposed)
// [+64K, +128K)        : Gl_t f16 [256 s][128 d]  (lo * 4096, transposed)
// [+128K, +256K)       : Gt   f32 [256 s][128 d]  (exact, transposed)
// [2MiB, 2MiB+32MiB)   : packed sign bits, u32[1M rows][8]
// suspect MASK (u32[1M rows][8], 32MB) lives in d_out (dead until est).
#define QS_OFF     0
#define GH_OFF     (1u << 20)
#define GL_OFF     ((1u << 20) + (64u << 10))
#define GT_OFF     ((1u << 20) + (128u << 10))
#define PACKED_OFF (2u << 20)

// ------------------------------------------------------------------
// Sequential f32 dot, d-ascending, single-rounding FMA per step —
// bitwise-matches the numpy reference path (validated round 3).
__device__ __forceinline__ float seq_dot_np(const float* __restrict__ a,
                                            const float* __restrict__ gcol) {
  float acc = 0.0f;
  #pragma unroll 8
  for (int d = 0; d < DDIM; ++d)
    acc = __builtin_fmaf(a[d], gcol[d], acc);
  return acc;
}

// ------------------------------------------------------------------
// prep: q_sketch = q @ G  (f32 accumulate, store f16)
__global__ void prep_qs_kernel(const float* __restrict__ q,
                               const float* __restrict__ G,
                               f16* __restrict__ qs16) {
  int idx = blockIdx.x * 256 + threadIdx.x;      // 524288
  int s  = idx & 255;
  int hq = idx >> 8;
  const float* qr = q + (size_t)hq * DDIM;
  float acc = 0.f;
  #pragma unroll 8
  for (int d = 0; d < DDIM; ++d) acc += qr[d] * G[d * SDIM + s];
  qs16[idx] = (f16)acc;
}

// prep: G -> f16 transposed hi + f16 transposed (lo*4096) + f32 exact copy
__global__ void prep_g_kernel(const float* __restrict__ G,
                              f16* __restrict__ gh, f16* __restrict__ gl,
                              float* __restrict__ gt) {
  int idx = blockIdx.x * 256 + threadIdx.x;      // 32768
  int d = idx & 127;
  int s = idx >> 7;
  float g = G[d * SDIM + s];
  f16 h = (f16)g;
  gh[s * DDIM + d] = h;
  gl[s * DDIM + d] = (f16)((g - (float)h) * 4096.0f);
  gt[s * DDIM + d] = g;
}

// ------------------------------------------------------------------
// Pass A: proj = k @ G via f16x3 MFMA emulation (validated arithmetic).
// 512-thr blocks (proven no-spill shape), 8 waves, 32 rows/wave,
// 256 rows/block, grid 4096. G processed in TWO s-phases of 128 each:
// LDS = 64KB -> 2 blocks/CU -> 16 waves/CU = 4 waves/SIMD (vs R9's 2).
// 6 independent MFMA chains per tile (ILP).
__launch_bounds__(512)
__global__ void proj_sign_kernel(const float* __restrict__ kmat,
                                 const f16* __restrict__ gh,
                                 const f16* __restrict__ gl,
                                 u32* __restrict__ packed,
                                 u32* __restrict__ smask) {
  __shared__ __align__(16) char smem[65536];     // Bh [0,32K) + Bl [32K,64K)

  const int tid  = threadIdx.x;
  const int lane = tid & 63;
  const int w    = tid >> 6;                     // wave 0..7
  const int g4 = lane >> 4;
  const int ln = lane & 15;

  const int base = blockIdx.x * 256 + w * 32;    // this wave's 32 rows

  // ---- A fragments (hi/lo f16 split) for 32 rows (2 blocks of 16) ----
  // A[m][kk]: m = lane&15, kk = 8*(lane>>4)+j  — loaded once, live across phases
  f16x8 Ah[2][4], Al[2][4];
  #pragma unroll
  for (int rb = 0; rb < 2; ++rb) {
    const float* kr = kmat + (size_t)(base + rb * 16 + ln) * DDIM;
    #pragma unroll
    for (int c = 0; c < 4; ++c) {
      const float* p0 = kr + c * 32 + g4 * 8;
      float4 a0 = *(const float4*)p0;
      float4 a1 = *(const float4*)(p0 + 4);
      float af[8] = {a0.x, a0.y, a0.z, a0.w, a1.x, a1.y, a1.z, a1.w};
      f16x8 hh, ll;
      #pragma unroll
      for (int j = 0; j < 8; ++j) {
        f16 h = (f16)af[j];
        hh[j] = h;
        ll[j] = (f16)((af[j] - (float)h) * 4096.0f);
      }
      Ah[rb][c] = hh;
      Al[rb][c] = ll;
    }
  }

  u32 pw[2][8] = {{0}};   // packed sign words  (lane<16: row rb*16+lane)
  u32 sw[2][8] = {{0}};   // suspect mask words

  for (int ph = 0; ph < 2; ++ph) {
    if (ph) __syncthreads();                     // all waves done reading ph-1
    // ---- stage 128-s phase of Gh/Gl, swizzled; 4 x 16B per thread/buffer ----
    {
      const f16* ghp = gh + (size_t)ph * 128 * DDIM;
      const f16* glp = gl + (size_t)ph * 128 * DDIM;
      #pragma unroll
      for (int j = 0; j < 4; ++j) {
        int cidx = j * 512 + tid;                // 2048 chunks of 16B
        int sl = cidx >> 4;                      // local s row 0..127
        int off = (cidx * 16) ^ ((sl & 7) << 4);
        *(f16x8*)(smem + off)         = *(const f16x8*)(ghp + (size_t)cidx * 8);
        *(f16x8*)(smem + 32768 + off) = *(const f16x8*)(glp + (size_t)cidx * 8);
      }
    }
    __syncthreads();

    #pragma unroll
    for (int tl = 0; tl < 8; ++tl) {             // 8 s-tiles of 16 per phase
      const int sl = tl * 16 + ln;               // local s row
      const int sx = (sl & 7) << 4;              // XOR swizzle
      const int gtl = ph * 8 + tl;               // global tile 0..15
      f16x8 Bh[4], Bl[4];
      #pragma unroll
      for (int c = 0; c < 4; ++c) {
        int off = (sl * 256 + c * 64 + g4 * 16) ^ sx;
        Bh[c] = *(const f16x8*)(smem + off);
        Bl[c] = *(const f16x8*)(smem + 32768 + off);
      }
      // f16x3 emulation, 6 INDEPENDENT 4-MFMA chains (ILP). Summation
      // order differs from np; fine since emul err ~1e-6 << TAU.
      f32x4 ah0 = {0,0,0,0}, aa0 = {0,0,0,0}, ab0 = {0,0,0,0};
      f32x4 ah1 = {0,0,0,0}, aa1 = {0,0,0,0}, ab1 = {0,0,0,0};
      #pragma unroll
      for (int c = 0; c < 4; ++c) {
        ah0 = __builtin_amdgcn_mfma_f32_16x16x32_f16(Ah[0][c], Bh[c], ah0, 0, 0, 0);
        aa0 = __builtin_amdgcn_mfma_f32_16x16x32_f16(Ah[0][c], Bl[c], aa0, 0, 0, 0);
        ab0 = __builtin_amdgcn_mfma_f32_16x16x32_f16(Al[0][c], Bh[c], ab0, 0, 0, 0);
        ah1 = __builtin_amdgcn_mfma_f32_16x16x32_f16(Ah[1][c], Bh[c], ah1, 0, 0, 0);
        aa1 = __builtin_amdgcn_mfma_f32_16x16x32_f16(Ah[1][c], Bl[c], aa1, 0, 0, 0);
        ab1 = __builtin_amdgcn_mfma_f32_16x16x32_f16(Al[1][c], Bh[c], ab1, 0, 0, 0);
      }
      float p[2][4];
      #pragma unroll
      for (int r = 0; r < 4; ++r) {
        p[0][r] = ah0[r] + (aa0[r] + ab0[r]) * 2.44140625e-4f;   // 1/4096
        p[1][r] = ah1[r] + (aa1[r] + ab1[r]) * 2.44140625e-4f;
      }

      // ---- sign ballots ----
      #pragma unroll
      for (int rb = 0; rb < 2; ++rb) {
        u64 b0 = __ballot(p[rb][0] > 0.0f ? 1 : 0);
        u64 b1 = __ballot(p[rb][1] > 0.0f ? 1 : 0);
        u64 b2 = __ballot(p[rb][2] > 0.0f ? 1 : 0);
        u64 b3 = __ballot(p[rb][3] > 0.0f ? 1 : 0);
        if (lane < 16) {
          int r = lane & 3;
          u64 b = (r == 0) ? b0 : (r == 1) ? b1 : (r == 2) ? b2 : b3;
          u32 sh = 16u * (u32)(lane >> 2);
          pw[rb][gtl >> 1] |= ((u32)((b >> sh) & 0xffffu)) << (16 * (gtl & 1));
        }
      }

      // ---- suspect ballots, guarded (trip prob ~1% per tile at 2e-5) ----
      float mn = __builtin_fabsf(p[0][0]);
      #pragma unroll
      for (int rb = 0; rb < 2; ++rb)
        #pragma unroll
        for (int r = 0; r < 4; ++r)
          mn = fminf(mn, __builtin_fabsf(p[rb][r]));
      if (__any(mn < TAU ? 1 : 0)) {
        #pragma unroll
        for (int rb = 0; rb < 2; ++rb) {
          u64 t0 = __ballot(__builtin_fabsf(p[rb][0]) < TAU ? 1 : 0);
          u64 t1 = __ballot(__builtin_fabsf(p[rb][1]) < TAU ? 1 : 0);
          u64 t2 = __ballot(__builtin_fabsf(p[rb][2]) < TAU ? 1 : 0);
          u64 t3 = __ballot(__builtin_fabsf(p[rb][3]) < TAU ? 1 : 0);
          if (lane < 16) {
            int r = lane & 3;
            u64 t = (r == 0) ? t0 : (r == 1) ? t1 : (r == 2) ? t2 : t3;
            u32 sh = 16u * (u32)(lane >> 2);
            sw[rb][gtl >> 1] |= ((u32)((t >> sh) & 0xffffu)) << (16 * (gtl & 1));
          }
        }
      }
    }
  }

  if (lane < 16) {
    #pragma unroll
    for (int rb = 0; rb < 2; ++rb) {
      size_t row = (size_t)(base + rb * 16 + lane);
      uint4 v0, v1, m0, m1;
      v0.x = pw[rb][0]; v0.y = pw[rb][1]; v0.z = pw[rb][2]; v0.w = pw[rb][3];
      v1.x = pw[rb][4]; v1.y = pw[rb][5]; v1.z = pw[rb][6]; v1.w = pw[rb][7];
      m0.x = sw[rb][0]; m0.y = sw[rb][1]; m0.z = sw[rb][2]; m0.w = sw[rb][3];
      m1.x = sw[rb][4]; m1.y = sw[rb][5]; m1.z = sw[rb][6]; m1.w = sw[rb][7];
      *(uint4*)(packed + row * 8)     = v0;
      *(uint4*)(packed + row * 8 + 4) = v1;
      *(uint4*)(smask  + row * 8)     = m0;
      *(uint4*)(smask  + row * 8 + 4) = m1;
    }
  }
}

// ------------------------------------------------------------------
// Pass B: one thread per k-row; ~6K suspects total -> mask-scan bound.
__global__ void fixup_kernel(const float* __restrict__ kmat,
                             const float* __restrict__ gt,
                             u32* __restrict__ packed,
                             const u32* __restrict__ smask) {
  int row = blockIdx.x * 256 + threadIdx.x;
  if (row >= NROWS) return;
  const u32* mp = smask + (size_t)row * 8;
  uint4 m0 = *(const uint4*)mp;
  uint4 m1 = *(const uint4*)(mp + 4);
  u32 mw[8] = {m0.x, m0.y, m0.z, m0.w, m1.x, m1.y, m1.z, m1.w};
  if (!(mw[0] | mw[1] | mw[2] | mw[3] | mw[4] | mw[5] | mw[6] | mw[7])) return;
  const float* a = kmat + (size_t)row * DDIM;
  #pragma unroll
  for (int wd = 0; wd < 8; ++wd) {
    u32 m = mw[wd];
    if (!m) continue;
    u32 pk = packed[(size_t)row * 8 + wd];
    while (m) {
      int b = __ffs(m) - 1;  m &= m - 1;
      int s = wd * 32 + b;
      float acc = seq_dot_np(a, gt + (size_t)s * DDIM);
      if (acc > 0.0f) pk |= (1u << b);
      else            pk &= ~(1u << b);
    }
    packed[(size_t)row * 8 + wd] = pk;
  }
}

// ------------------------------------------------------------------
// est = q_sketch @ sign^T, bits -> ±1 f16 on the fly, MFMA f16, f32 out
__launch_bounds__(256)
__global__ void est_kernel(const f16* __restrict__ qs16,
                           const u32* __restrict__ packed,
                           float* __restrict__ out) {
  const int tid  = threadIdx.x;
  const int lane = tid & 63;
  const int w    = tid >> 6;
  const int wg   = blockIdx.x;
  const int head   = wg >> 5;
  const int kchunk = (wg & 31) * 256;
  const int g4 = lane >> 4, ln = lane & 15;

  f16x8 aq[8];
  const f16* qb = qs16 + (size_t)head * 16 * SDIM;
  #pragma unroll
  for (int c = 0; c < 8; ++c)
    aq[c] = *(const f16x8*)(qb + ln * SDIM + c * 32 + g4 * 8);

  const int kb = kchunk + w * 64;
  #pragma unroll
  for (int kt = 0; kt < 4; ++kt) {
    int krow = kb + kt * 16 + ln;
    const u32* bp = packed + (size_t)(head * KLEN + krow) * 8;
    uint4 q0 = *(const uint4*)bp;
    uint4 q1 = *(const uint4*)(bp + 4);
    u32 b32[8] = {q0.x, q0.y, q0.z, q0.w, q1.x, q1.y, q1.z, q1.w};
    f32x4 acc = {0, 0, 0, 0};
    #pragma unroll
    for (int c = 0; c < 8; ++c) {
      u32 byte8 = (b32[c] >> (8 * g4)) & 0xffu;
      union { u32 u[4]; f16x8 h; } sv;
      #pragma unroll
      for (int pp = 0; pp < 4; ++pp) {
        u32 v = 0x3C003C00u;
        v |= ((byte8 >> (2 * pp))     & 1u) ? 0u : 0x8000u;
        v |= ((byte8 >> (2 * pp + 1)) & 1u) ? 0u : 0x80000000u;
        sv.u[pp] = v;
      }
      acc = __builtin_amdgcn_mfma_f32_16x16x32_f16(aq[c], sv.h, acc, 0, 0, 0);
    }
    float* ob = out + (size_t)(head * 16) * KLEN + kb + kt * 16 + ln;
    #pragma unroll
    for (int r = 0; r < 4; ++r) {
      int qrow = g4 * 4 + r;
      ob[(size_t)qrow * KLEN] = acc[r] * SCALE;
    }
  }
}

// ------------------------------------------------------------------
extern "C" void kernel_launch(void* const* d_in, const int* in_sizes, int n_in,
                              void* d_out, int out_size, void* d_ws, size_t ws_size,
                              hipStream_t stream) {
  const float* q = (const float*)d_in[0];
  const float* k = (const float*)d_in[1];
  const float* G = (const float*)d_in[2];
  float* out = (float*)d_out;
  char* ws = (char*)d_ws;

  f16*   qs16   = (f16*)(ws + QS_OFF);
  f16*   gh     = (f16*)(ws + GH_OFF);
  f16*   gl     = (f16*)(ws + GL_OFF);
  float* gt     = (float*)(ws + GT_OFF);
  u32*   packed = (u32*)(ws + PACKED_OFF);

  // suspect mask in d_out (32MB << 67MB); fully rewritten by proj_sign
  // each call; est overwrites d_out afterwards (stream-ordered).
  u32* smask = (u32*)d_out;

  prep_qs_kernel<<<2048, 256, 0, stream>>>(q, G, qs16);
  prep_g_kernel<<<128, 256, 0, stream>>>(G, gh, gl, gt);
  proj_sign_kernel<<<4096, 512, 0, stream>>>(k, gh, gl, packed, smask);
  fixup_kernel<<<4096, 256, 0, stream>>>(k, gt, packed, smask);
  est_kernel<<<4096, 256, 0, stream>>>(qs16, packed, out);
}